// Round 8
// baseline (2954.240 us; speedup 1.0000x reference)
//
#include <hip/hip_runtime.h>
#include <hip/hip_bf16.h>
#include <math.h>

#define TLEN 1022
#define SLEN 1024
#define NB   64
#define NE   256
#define NF   256
#define NH   256
#define NG   1024
#define TC   256      // chunk length (last chunk = 254)

typedef _Float16 h2_t __attribute__((ext_vector_type(2)));
typedef __attribute__((ext_vector_type(8))) short bf16x8;
typedef __attribute__((ext_vector_type(4))) float f32x4;

#if defined(__has_builtin)
# if __has_builtin(__builtin_amdgcn_fdot2)
#  define HAVE_FDOT2 1
# endif
#endif
#ifndef HAVE_FDOT2
# define HAVE_FDOT2 0
#endif

__device__ __forceinline__ float sigm(float x){ return 1.f/(1.f+__expf(-x)); }
__device__ __forceinline__ float tanh_(float x){ return 1.f - 2.f/(__expf(2.f*x)+1.f); }

__device__ __forceinline__ unsigned int packh2(float x, float y){
  h2_t p; p.x = (_Float16)x; p.y = (_Float16)y;
  return __builtin_bit_cast(unsigned int, p);
}
__device__ __forceinline__ float dot2_acc(unsigned int w, unsigned int h, float acc){
  h2_t a = __builtin_bit_cast(h2_t, w);
  h2_t b = __builtin_bit_cast(h2_t, h);
#if HAVE_FDOT2
  return __builtin_amdgcn_fdot2(a, b, acc, false);
#else
  return acc + (float)a.x*(float)b.x + (float)a.y*(float)b.y;
#endif
}
__device__ __forceinline__ unsigned short f2bf(float x){
  __hip_bfloat16 b = __float2bfloat16(x);
  return __builtin_bit_cast(unsigned short, b);
}

// bias4[g] = b_ih[g] + b_hh[g] + sum_f conv_b[f]*w_ih[g][f]
__global__ __launch_bounds__(256) void k_bias(const float* __restrict__ conv_b,
                                              const float* __restrict__ w_ih,
                                              const float* __restrict__ b_ih,
                                              const float* __restrict__ b_hh,
                                              float* __restrict__ bias4){
  int g = blockIdx.x*256 + threadIdx.x;
  const float* row = w_ih + (size_t)g*NF;
  float s = b_ih[g] + b_hh[g];
  for (int f=0; f<NF; f+=4){
    float4 w4 = *(const float4*)(row+f);
    float4 c4 = *(const float4*)(conv_b+f);
    s += w4.x*c4.x + w4.y*c4.y + w4.z*c4.z + w4.w*c4.w;
  }
  bias4[g] = s;
}

// Prepack w_hh (fp32 [1024][256]) into per-thread f16-pair layout (512-thread k_rnn):
// pall4[j][tid], j<64, tid<512. Thread tid=(wv*64+l): kq=wv>>1, jh=wv&1.
// pair idx = 4j+e, cp = idx>>3 (0..31), r = idx&7; row = jh*512 + l*8 + r;
// cols = kq*64 + 2cp, +1.
__global__ __launch_bounds__(256) void k_pack(const float* __restrict__ w_hh,
                                              uint4* __restrict__ pall4){
  int gid = blockIdx.x*256 + threadIdx.x;     // 0..32767
  int tid = gid & 511, j = gid >> 9;
  int l = tid & 63, wv = tid >> 6, kq = wv >> 1, jh = wv & 1;
  unsigned int c[4];
  #pragma unroll
  for (int e=0;e<4;++e){
    int idx = 4*j + e, cp = idx >> 3, r = idx & 7;
    int row = jh*512 + l*8 + r, col = kq*64 + 2*cp;
    const float* p = w_hh + (size_t)row*NH + col;
    c[e] = packh2(p[0], p[1]);
  }
  pall4[(size_t)j*512 + tid] = make_uint4(c[0],c[1],c[2],c[3]);
}

// CW2T[g][k] = sum_f w_ih[g][f] * conv_w_flat[k][f]   (M=1024 g, N=768 k, K=256 f)
// bf16 output, row-major [1024][768].
__global__ __launch_bounds__(256) void k_cw2(const float* __restrict__ w_ih,
                                             const float* __restrict__ conv_w,
                                             unsigned short* __restrict__ cw2t){
  __shared__ float al[64][17];
  __shared__ float bl[16][64];
  const int n0  = blockIdx.x*64;   // k-dim (768)
  const int m0  = blockIdx.y*64;   // g-dim (1024)
  const int tid = threadIdx.x;
  const int ty  = tid>>4, tx = tid&15;
  const int rr  = tid>>2, kq = (tid&3)<<2;
  float acc[4][4];
  #pragma unroll
  for (int i=0;i<4;++i){ acc[i][0]=0.f; acc[i][1]=0.f; acc[i][2]=0.f; acc[i][3]=0.f; }

  for (int k0=0; k0<256; k0+=16){
    __syncthreads();
    {
      float4 v = *(const float4*)(w_ih + (size_t)(m0+rr)*NF + k0 + kq);
      al[rr][kq+0]=v.x; al[rr][kq+1]=v.y; al[rr][kq+2]=v.z; al[rr][kq+3]=v.w;
      float4 u = *(const float4*)(conv_w + (size_t)(n0+rr)*NF + k0 + kq);
      bl[kq+0][rr]=u.x; bl[kq+1][rr]=u.y; bl[kq+2][rr]=u.z; bl[kq+3][rr]=u.w;
    }
    __syncthreads();
    #pragma unroll
    for (int kk=0; kk<16; ++kk){
      float a0=al[ty*4+0][kk], a1=al[ty*4+1][kk], a2=al[ty*4+2][kk], a3=al[ty*4+3][kk];
      float4 bv = *(const float4*)&bl[kk][tx*4];
      acc[0][0]+=a0*bv.x; acc[0][1]+=a0*bv.y; acc[0][2]+=a0*bv.z; acc[0][3]+=a0*bv.w;
      acc[1][0]+=a1*bv.x; acc[1][1]+=a1*bv.y; acc[1][2]+=a1*bv.z; acc[1][3]+=a1*bv.w;
      acc[2][0]+=a2*bv.x; acc[2][1]+=a2*bv.y; acc[2][2]+=a2*bv.z; acc[2][3]+=a2*bv.w;
      acc[3][0]+=a3*bv.x; acc[3][1]+=a3*bv.y; acc[3][2]+=a3*bv.z; acc[3][3]+=a3*bv.w;
    }
  }
  #pragma unroll
  for (int i=0;i<4;++i){
    size_t r = (size_t)m0 + ty*4 + i;
    unsigned int p0 = (unsigned int)f2bf(acc[i][0]) | ((unsigned int)f2bf(acc[i][1])<<16);
    unsigned int p1 = (unsigned int)f2bf(acc[i][2]) | ((unsigned int)f2bf(acc[i][3])<<16);
    *(uint2*)(cw2t + r*768 + n0 + tx*4) = make_uint2(p0, p1);
  }
}

// Fused conv+xg GEMM: xh[m][g] = f16( sum_k A[m][k]*CW2T[g][k] + bias4[g] )
// A[m][k] = emb[ tok(b, t0+tl+w) ][e],  m=(tl*64+b), k=w*256+e.  M=16384, K=768, N=1024.
// Tile 128(m) x 256(n), BK=64. 4 waves, each 64x128 (acc[4][8]).
__global__ __launch_bounds__(256,2) void k_fxg(const int* __restrict__ ipts,
                                               const float* __restrict__ emb,
                                               const unsigned short* __restrict__ cw2t,
                                               const float* __restrict__ bias4,
                                               unsigned short* __restrict__ xh,
                                               int t0){
  __shared__ unsigned short A_l[128][72];   // [m][k] bf16, pad 72
  __shared__ unsigned short B_l[256][72];   // [n][k] bf16, pad 72
  __shared__ int tokl[4][64];
  const int tid = threadIdx.x;
  const int l   = tid & 63, wv = tid >> 6;
  const int m0  = blockIdx.x * 128;
  const int n0  = blockIdx.y * 256;
  const int TL0 = m0 >> 6;
  {
    int tv = tid >> 6, b = tid & 63;
    tokl[tv][b] = ipts[b*SLEN + t0 + TL0 + tv];
  }

  f32x4 acc[4][8];
  #pragma unroll
  for (int mt=0; mt<4; ++mt)
    #pragma unroll
    for (int nt=0; nt<8; ++nt)
      acc[mt][nt] = (f32x4){0.f,0.f,0.f,0.f};

  const int wm = wv >> 1, wn = wv & 1;
  const int lr = l & 15, lk = l >> 4;

  for (int ks = 0; ks < 12; ++ks){
    const int w0 = ks >> 2;            // conv window position (0..2)
    const int e0 = (ks & 3) << 6;      // emb col base
    __syncthreads();
    // ---- stage A: gather emb rows, convert fp32->bf16 ----
    #pragma unroll
    for (int s = 0; s < 4; ++s){
      int seg = tid + s*256;
      int row = seg >> 3, off = seg & 7;
      int tok = tokl[(row>>6) + w0][row & 63];
      const float* src = emb + (size_t)tok*NE + e0 + off*8;
      float4 f0 = *(const float4*)src;
      float4 f1 = *(const float4*)(src+4);
      unsigned int p0 = (unsigned int)f2bf(f0.x) | ((unsigned int)f2bf(f0.y)<<16);
      unsigned int p1 = (unsigned int)f2bf(f0.z) | ((unsigned int)f2bf(f0.w)<<16);
      unsigned int p2 = (unsigned int)f2bf(f1.x) | ((unsigned int)f2bf(f1.y)<<16);
      unsigned int p3 = (unsigned int)f2bf(f1.z) | ((unsigned int)f2bf(f1.w)<<16);
      *(uint4*)&A_l[row][off*8] = make_uint4(p0,p1,p2,p3);
    }
    // ---- stage B: CW2T rows n0..n0+255, cols k0..k0+63 ----
    #pragma unroll
    for (int s = 0; s < 8; ++s){
      int seg = tid + s*256;
      int row = seg >> 3, off = seg & 7;
      uint4 v = *(const uint4*)(cw2t + (size_t)(n0+row)*768 + (ks<<6) + off*8);
      *(uint4*)&B_l[row][off*8] = v;
    }
    __syncthreads();
    // ---- MFMA ----
    #pragma unroll
    for (int kf = 0; kf < 2; ++kf){
      bf16x8 af[4], bfr[8];
      #pragma unroll
      for (int mt=0; mt<4; ++mt)
        af[mt] = *(const bf16x8*)&A_l[wm*64 + mt*16 + lr][kf*32 + lk*8];
      #pragma unroll
      for (int nt=0; nt<8; ++nt)
        bfr[nt] = *(const bf16x8*)&B_l[wn*128 + nt*16 + lr][kf*32 + lk*8];
      #pragma unroll
      for (int mt=0; mt<4; ++mt)
        #pragma unroll
        for (int nt=0; nt<8; ++nt)
          acc[mt][nt] = __builtin_amdgcn_mfma_f32_16x16x32_bf16(af[mt], bfr[nt], acc[mt][nt], 0,0,0);
    }
  }

  // ---- epilogue: +bias, f16, store ----
  float bia[8];
  #pragma unroll
  for (int nt=0; nt<8; ++nt) bia[nt] = bias4[n0 + wn*128 + nt*16 + lr];
  #pragma unroll
  for (int mt=0; mt<4; ++mt){
    #pragma unroll
    for (int nt=0; nt<8; ++nt){
      #pragma unroll
      for (int r=0; r<4; ++r){
        int row = m0 + wm*64 + mt*16 + lk*4 + r;
        int col = n0 + wn*128 + nt*16 + lr;
        _Float16 hv = (_Float16)(acc[mt][nt][r] + bia[nt]);
        xh[(size_t)row*NG + col] = __builtin_bit_cast(unsigned short, hv);
      }
    }
  }
}

// LSTM chunk. 64 WGs x 512 threads (8 waves, 2/SIMD).
// wave wv: kq=wv>>1 (col slice 64), jh=wv&1 (row half). thread l: rows jh*512+l*8+r.
// Weight residency (256 pairs/thread), ALL on-CU:
//   cp in [0,8)  -> LDS wlds4[16][512] (128 KB)
//   cp in [8,32) -> 192 AGPRs via inline v_accvgpr_write/read ("=a" class):
//                   the arch-VGPR RA ceiling (128) doesn't govern AGPRs, and
//                   asm-defined AGPR values cannot be rematerialized.
__global__ __attribute__((amdgpu_flat_work_group_size(512,512)))
__attribute__((amdgpu_waves_per_eu(2,2)))
void k_rnn(const unsigned short* __restrict__ xh,
           const uint4* __restrict__ pall4,
           const float* __restrict__ h0,
           const float* __restrict__ c0,
           const int* __restrict__ seqlen,
           const float* __restrict__ lin_w,
           const float* __restrict__ lin_b,
           unsigned int* __restrict__ h_ws,
           float* __restrict__ c_ws,
           float* __restrict__ ms_ws,
           float* __restrict__ out,
           int t0, int tcount, int is_first, int is_last){
  __shared__ uint4 wlds4[16][512];          // 128 KB: weight pairs for cp in [0,8)
  __shared__ unsigned int hp[128];          // h as f16 pairs
  __shared__ float part2[4][2][8][68];      // [kq][jh][r][l] pitch 68
  __shared__ float red[256];
  const int b   = blockIdx.x;
  const int tid = threadIdx.x;
  const int l   = tid & 63, wv = tid >> 6;
  const int kq  = wv >> 1, jh = wv & 1;

  // stage LDS-resident weights (j = 0..15 -> cp in [0,8))
  #pragma unroll
  for (int jj=0; jj<16; ++jj)
    wlds4[jj][tid] = pall4[(size_t)jj*512 + tid];

  // AGPR-resident weights (j = 16..63 -> cp in [8,32)): wa[(cp-8)*8 + r]
  unsigned int wa[192];
  #pragma unroll
  for (int j=16; j<64; ++j){
    uint4 v = pall4[(size_t)j*512 + tid];
    asm volatile("v_accvgpr_write_b32 %0, %1" : "=a"(wa[4*(j-16)+0]) : "v"(v.x));
    asm volatile("v_accvgpr_write_b32 %0, %1" : "=a"(wa[4*(j-16)+1]) : "v"(v.y));
    asm volatile("v_accvgpr_write_b32 %0, %1" : "=a"(wa[4*(j-16)+2]) : "v"(v.z));
    asm volatile("v_accvgpr_write_b32 %0, %1" : "=a"(wa[4*(j-16)+3]) : "v"(v.w));
  }

  float creg = 0.f, msum = 0.f;
  if (is_first){
    if (tid < 128) hp[tid] = packh2(h0[(size_t)b*NH + 2*tid], h0[(size_t)b*NH + 2*tid + 1]);
    if (tid < 256) creg = c0[(size_t)b*NH + tid];
  } else {
    if (tid < 128) hp[tid] = h_ws[b*128 + tid];
    if (tid < 256){ creg = c_ws[b*256 + tid]; msum = ms_ws[b*256 + tid]; }
  }
  const int L = seqlen[b];
  __syncthreads();

  const unsigned short* xrow = xh + (size_t)b*NG + tid;

  for (int tl=0; tl<tcount; ++tl){
    // ---- prefetch xg for this step (raw; converted after barrier) ----
    unsigned short xr0=0, xr1=0, xr2=0, xr3=0;
    if (tid < 256){
      const unsigned short* xr = xrow + (size_t)tl*NB*NG;
      xr0 = xr[0]; xr1 = xr[256]; xr2 = xr[512]; xr3 = xr[768];
    }

    float pa[8];
    #pragma unroll
    for (int r=0;r<8;++r) pa[r]=0.f;

    // MAC over cp = 0..31; h pairs read 4-at-a-time as b128 broadcasts
    #pragma unroll
    for (int c=0; c<8; ++c){
      uint4 hv = *(const uint4*)&hp[kq*32 + 4*c];
      unsigned int hvv[4] = {hv.x, hv.y, hv.z, hv.w};
      #pragma unroll
      for (int e=0; e<4; ++e){
        const int cp = 4*c + e;
        if (cp < 8){
          uint4 w0 = wlds4[2*cp][tid];
          uint4 w1 = wlds4[2*cp+1][tid];
          pa[0] = dot2_acc(w0.x, hvv[e], pa[0]);
          pa[1] = dot2_acc(w0.y, hvv[e], pa[1]);
          pa[2] = dot2_acc(w0.z, hvv[e], pa[2]);
          pa[3] = dot2_acc(w0.w, hvv[e], pa[3]);
          pa[4] = dot2_acc(w1.x, hvv[e], pa[4]);
          pa[5] = dot2_acc(w1.y, hvv[e], pa[5]);
          pa[6] = dot2_acc(w1.z, hvv[e], pa[6]);
          pa[7] = dot2_acc(w1.w, hvv[e], pa[7]);
        } else {
          #pragma unroll
          for (int r=0; r<8; ++r){
            unsigned int t;
            asm volatile("v_accvgpr_read_b32 %0, %1" : "=v"(t) : "a"(wa[(cp-8)*8 + r]));
            pa[r] = dot2_acc(t, hvv[e], pa[r]);
          }
        }
      }
    }

    #pragma unroll
    for (int r=0;r<8;++r) part2[kq][jh][r][l] = pa[r];
    __syncthreads();

    if (tid < 256){
      unsigned short xr4[4] = {xr0, xr1, xr2, xr3};
      float a[4];
      #pragma unroll
      for (int q=0;q<4;++q){
        int G = q*256 + tid;
        int jh2 = G>>9, rw = G&511, l2 = rw>>3, r2 = rw&7;
        float s = (float)__builtin_bit_cast(_Float16, xr4[q]);
        #pragma unroll
        for (int k=0;k<4;++k) s += part2[k][jh2][r2][l2];
        a[q] = s;
      }
      float si = sigm(a[0]), sf = sigm(a[1]), so = sigm(a[3]);
      float tg = tanh_(a[2]);
      creg = sf*creg + si*tg;
      float h2 = so*tanh_(creg);
      if (t0 + tl < L) msum += h2;
      ((_Float16*)hp)[tid] = (_Float16)h2;
    }
    __syncthreads();
  }

  if (tid < 128) h_ws[b*128 + tid] = hp[tid];
  if (tid < 256){ c_ws[b*256 + tid] = creg; ms_ws[b*256 + tid] = msum; }

  if (is_last){
    if (tid < 256) red[tid] = (msum / (float)L) * lin_w[tid];
    __syncthreads();
    if (tid < 64){
      float s = red[tid] + red[tid+64] + red[tid+128] + red[tid+192];
      #pragma unroll
      for (int off=32; off>0; off>>=1) s += __shfl_down(s, off);
      if (tid==0) out[b] = sigm(s + lin_b[0]);
    }
  }
}

extern "C" void kernel_launch(void* const* d_in, const int* in_sizes, int n_in,
                              void* d_out, int out_size, void* d_ws, size_t ws_size,
                              hipStream_t stream){
  const int*   ipts   = (const int*)d_in[0];
  const int*   seqlen = (const int*)d_in[1];
  const float* h0     = (const float*)d_in[2];
  const float* c0     = (const float*)d_in[3];
  const float* emb    = (const float*)d_in[4];
  const float* conv_w = (const float*)d_in[5];
  const float* conv_b = (const float*)d_in[6];
  const float* w_ih   = (const float*)d_in[7];
  const float* w_hh   = (const float*)d_in[8];
  const float* b_ih   = (const float*)d_in[9];
  const float* b_hh   = (const float*)d_in[10];
  const float* lin_w  = (const float*)d_in[11];
  const float* lin_b  = (const float*)d_in[12];
  float* out = (float*)d_out;

  char* ws = (char*)d_ws;
  const size_t XH_B   = (size_t)TC*NB*NG*2;      // 33.5 MB
  const size_t CW2_B  = (size_t)NG*768*2;        // 1.57 MB
  const size_t PALL_B = (size_t)64*512*16;       // 512 KB
  unsigned short* xh    = (unsigned short*)ws;
  unsigned short* cw2t  = (unsigned short*)(ws + XH_B);
  uint4*          pall4 = (uint4*)(ws + XH_B + CW2_B);
  float*          bias4 = (float*)(ws + XH_B + CW2_B + PALL_B);
  unsigned int*   h_ws  = (unsigned int*)(ws + XH_B + CW2_B + PALL_B + 4096);
  float*          c_ws  = (float*)(ws + XH_B + CW2_B + PALL_B + 4096 + 32768);
  float*          ms_ws = (float*)(ws + XH_B + CW2_B + PALL_B + 4096 + 32768 + 65536);

  k_bias<<<dim3(4),       dim3(256), 0, stream>>>(conv_b, w_ih, b_ih, b_hh, bias4);
  k_pack<<<dim3(128),     dim3(256), 0, stream>>>(w_hh, pall4);
  k_cw2 <<<dim3(12, 16),  dim3(256), 0, stream>>>(w_ih, conv_w, cw2t);

  for (int t0 = 0; t0 < TLEN; t0 += TC){
    int tcount = (TLEN - t0 < TC) ? (TLEN - t0) : TC;
    int is_first = (t0 == 0), is_last = (t0 + TC >= TLEN);
    k_fxg<<<dim3(128, 4), dim3(256), 0, stream>>>(ipts, emb, cw2t, bias4, xh, t0);
    k_rnn<<<dim3(NB),     dim3(512), 0, stream>>>(xh, pall4, h0, c0, seqlen,
                                                  lin_w, lin_b, h_ws, c_ws, ms_ws, out,
                                                  t0, tcount, is_first, is_last);
  }
}

// Round 9
// 2781.725 us; speedup vs baseline: 1.0620x; 1.0620x over previous
//
#include <hip/hip_runtime.h>
#include <hip/hip_bf16.h>
#include <math.h>

#define TLEN 1022
#define SLEN 1024
#define NB   64
#define NE   256
#define NF   256
#define NH   256
#define NG   1024
#define TC   256      // chunk length (last chunk = 254)

typedef _Float16 h2_t __attribute__((ext_vector_type(2)));
typedef __attribute__((ext_vector_type(8))) short bf16x8;
typedef __attribute__((ext_vector_type(4))) float f32x4;

#if defined(__has_builtin)
# if __has_builtin(__builtin_amdgcn_fdot2)
#  define HAVE_FDOT2 1
# endif
#endif
#ifndef HAVE_FDOT2
# define HAVE_FDOT2 0
#endif

__device__ __forceinline__ float sigm(float x){ return 1.f/(1.f+__expf(-x)); }
__device__ __forceinline__ float tanh_(float x){ return 1.f - 2.f/(__expf(2.f*x)+1.f); }

__device__ __forceinline__ unsigned int packh2(float x, float y){
  h2_t p; p.x = (_Float16)x; p.y = (_Float16)y;
  return __builtin_bit_cast(unsigned int, p);
}
__device__ __forceinline__ float dot2_acc(unsigned int w, unsigned int h, float acc){
  h2_t a = __builtin_bit_cast(h2_t, w);
  h2_t b = __builtin_bit_cast(h2_t, h);
#if HAVE_FDOT2
  return __builtin_amdgcn_fdot2(a, b, acc, false);
#else
  return acc + (float)a.x*(float)b.x + (float)a.y*(float)b.y;
#endif
}
__device__ __forceinline__ unsigned short f2bf(float x){
  __hip_bfloat16 b = __float2bfloat16(x);
  return __builtin_bit_cast(unsigned short, b);
}

// bias4[g] = b_ih[g] + b_hh[g] + sum_f conv_b[f]*w_ih[g][f]
__global__ __launch_bounds__(256) void k_bias(const float* __restrict__ conv_b,
                                              const float* __restrict__ w_ih,
                                              const float* __restrict__ b_ih,
                                              const float* __restrict__ b_hh,
                                              float* __restrict__ bias4){
  int g = blockIdx.x*256 + threadIdx.x;
  const float* row = w_ih + (size_t)g*NF;
  float s = b_ih[g] + b_hh[g];
  for (int f=0; f<NF; f+=4){
    float4 w4 = *(const float4*)(row+f);
    float4 c4 = *(const float4*)(conv_b+f);
    s += w4.x*c4.x + w4.y*c4.y + w4.z*c4.z + w4.w*c4.w;
  }
  bias4[g] = s;
}

// Prepack w_hh (fp32 [1024][256]) into per-thread f16-pair layout (512-thread k_rnn):
// pall4[j][tid], j<64, tid<512. Thread tid=(wv*64+l): kq=wv>>1, jh=wv&1.
// pair idx = 4j+e, cp = idx>>3 (0..31), r = idx&7; row = jh*512 + l*8 + r;
// cols = kq*64 + 2cp, +1.
__global__ __launch_bounds__(256) void k_pack(const float* __restrict__ w_hh,
                                              uint4* __restrict__ pall4){
  int gid = blockIdx.x*256 + threadIdx.x;     // 0..32767
  int tid = gid & 511, j = gid >> 9;
  int l = tid & 63, wv = tid >> 6, kq = wv >> 1, jh = wv & 1;
  unsigned int c[4];
  #pragma unroll
  for (int e=0;e<4;++e){
    int idx = 4*j + e, cp = idx >> 3, r = idx & 7;
    int row = jh*512 + l*8 + r, col = kq*64 + 2*cp;
    const float* p = w_hh + (size_t)row*NH + col;
    c[e] = packh2(p[0], p[1]);
  }
  pall4[(size_t)j*512 + tid] = make_uint4(c[0],c[1],c[2],c[3]);
}

// CW2T[g][k] = sum_f w_ih[g][f] * conv_w_flat[k][f]   (M=1024 g, N=768 k, K=256 f)
// bf16 output, row-major [1024][768].
__global__ __launch_bounds__(256) void k_cw2(const float* __restrict__ w_ih,
                                             const float* __restrict__ conv_w,
                                             unsigned short* __restrict__ cw2t){
  __shared__ float al[64][17];
  __shared__ float bl[16][64];
  const int n0  = blockIdx.x*64;   // k-dim (768)
  const int m0  = blockIdx.y*64;   // g-dim (1024)
  const int tid = threadIdx.x;
  const int ty  = tid>>4, tx = tid&15;
  const int rr  = tid>>2, kq = (tid&3)<<2;
  float acc[4][4];
  #pragma unroll
  for (int i=0;i<4;++i){ acc[i][0]=0.f; acc[i][1]=0.f; acc[i][2]=0.f; acc[i][3]=0.f; }

  for (int k0=0; k0<256; k0+=16){
    __syncthreads();
    {
      float4 v = *(const float4*)(w_ih + (size_t)(m0+rr)*NF + k0 + kq);
      al[rr][kq+0]=v.x; al[rr][kq+1]=v.y; al[rr][kq+2]=v.z; al[rr][kq+3]=v.w;
      float4 u = *(const float4*)(conv_w + (size_t)(n0+rr)*NF + k0 + kq);
      bl[kq+0][rr]=u.x; bl[kq+1][rr]=u.y; bl[kq+2][rr]=u.z; bl[kq+3][rr]=u.w;
    }
    __syncthreads();
    #pragma unroll
    for (int kk=0; kk<16; ++kk){
      float a0=al[ty*4+0][kk], a1=al[ty*4+1][kk], a2=al[ty*4+2][kk], a3=al[ty*4+3][kk];
      float4 bv = *(const float4*)&bl[kk][tx*4];
      acc[0][0]+=a0*bv.x; acc[0][1]+=a0*bv.y; acc[0][2]+=a0*bv.z; acc[0][3]+=a0*bv.w;
      acc[1][0]+=a1*bv.x; acc[1][1]+=a1*bv.y; acc[1][2]+=a1*bv.z; acc[1][3]+=a1*bv.w;
      acc[2][0]+=a2*bv.x; acc[2][1]+=a2*bv.y; acc[2][2]+=a2*bv.z; acc[2][3]+=a2*bv.w;
      acc[3][0]+=a3*bv.x; acc[3][1]+=a3*bv.y; acc[3][2]+=a3*bv.z; acc[3][3]+=a3*bv.w;
    }
  }
  #pragma unroll
  for (int i=0;i<4;++i){
    size_t r = (size_t)m0 + ty*4 + i;
    unsigned int p0 = (unsigned int)f2bf(acc[i][0]) | ((unsigned int)f2bf(acc[i][1])<<16);
    unsigned int p1 = (unsigned int)f2bf(acc[i][2]) | ((unsigned int)f2bf(acc[i][3])<<16);
    *(uint2*)(cw2t + r*768 + n0 + tx*4) = make_uint2(p0, p1);
  }
}

// Fused conv+xg GEMM: xh[m][g] = f16( sum_k A[m][k]*CW2T[g][k] + bias4[g] )
// A[m][k] = emb[ tok(b, t0+tl+w) ][e],  m=(tl*64+b), k=w*256+e.  M=16384, K=768, N=1024.
// Tile 128(m) x 256(n), BK=64. 4 waves, each 64x128 (acc[4][8]).
__global__ __launch_bounds__(256,2) void k_fxg(const int* __restrict__ ipts,
                                               const float* __restrict__ emb,
                                               const unsigned short* __restrict__ cw2t,
                                               const float* __restrict__ bias4,
                                               unsigned short* __restrict__ xh,
                                               int t0){
  __shared__ unsigned short A_l[128][72];   // [m][k] bf16, pad 72
  __shared__ unsigned short B_l[256][72];   // [n][k] bf16, pad 72
  __shared__ int tokl[4][64];
  const int tid = threadIdx.x;
  const int l   = tid & 63, wv = tid >> 6;
  const int m0  = blockIdx.x * 128;
  const int n0  = blockIdx.y * 256;
  const int TL0 = m0 >> 6;
  {
    int tv = tid >> 6, b = tid & 63;
    tokl[tv][b] = ipts[b*SLEN + t0 + TL0 + tv];
  }

  f32x4 acc[4][8];
  #pragma unroll
  for (int mt=0; mt<4; ++mt)
    #pragma unroll
    for (int nt=0; nt<8; ++nt)
      acc[mt][nt] = (f32x4){0.f,0.f,0.f,0.f};

  const int wm = wv >> 1, wn = wv & 1;
  const int lr = l & 15, lk = l >> 4;

  for (int ks = 0; ks < 12; ++ks){
    const int w0 = ks >> 2;            // conv window position (0..2)
    const int e0 = (ks & 3) << 6;      // emb col base
    __syncthreads();
    // ---- stage A: gather emb rows, convert fp32->bf16 ----
    #pragma unroll
    for (int s = 0; s < 4; ++s){
      int seg = tid + s*256;
      int row = seg >> 3, off = seg & 7;
      int tok = tokl[(row>>6) + w0][row & 63];
      const float* src = emb + (size_t)tok*NE + e0 + off*8;
      float4 f0 = *(const float4*)src;
      float4 f1 = *(const float4*)(src+4);
      unsigned int p0 = (unsigned int)f2bf(f0.x) | ((unsigned int)f2bf(f0.y)<<16);
      unsigned int p1 = (unsigned int)f2bf(f0.z) | ((unsigned int)f2bf(f0.w)<<16);
      unsigned int p2 = (unsigned int)f2bf(f1.x) | ((unsigned int)f2bf(f1.y)<<16);
      unsigned int p3 = (unsigned int)f2bf(f1.z) | ((unsigned int)f2bf(f1.w)<<16);
      *(uint4*)&A_l[row][off*8] = make_uint4(p0,p1,p2,p3);
    }
    // ---- stage B: CW2T rows n0..n0+255, cols k0..k0+63 ----
    #pragma unroll
    for (int s = 0; s < 8; ++s){
      int seg = tid + s*256;
      int row = seg >> 3, off = seg & 7;
      uint4 v = *(const uint4*)(cw2t + (size_t)(n0+row)*768 + (ks<<6) + off*8);
      *(uint4*)&B_l[row][off*8] = v;
    }
    __syncthreads();
    // ---- MFMA ----
    #pragma unroll
    for (int kf = 0; kf < 2; ++kf){
      bf16x8 af[4], bfr[8];
      #pragma unroll
      for (int mt=0; mt<4; ++mt)
        af[mt] = *(const bf16x8*)&A_l[wm*64 + mt*16 + lr][kf*32 + lk*8];
      #pragma unroll
      for (int nt=0; nt<8; ++nt)
        bfr[nt] = *(const bf16x8*)&B_l[wn*128 + nt*16 + lr][kf*32 + lk*8];
      #pragma unroll
      for (int mt=0; mt<4; ++mt)
        #pragma unroll
        for (int nt=0; nt<8; ++nt)
          acc[mt][nt] = __builtin_amdgcn_mfma_f32_16x16x32_bf16(af[mt], bfr[nt], acc[mt][nt], 0,0,0);
    }
  }

  // ---- epilogue: +bias, f16, store ----
  float bia[8];
  #pragma unroll
  for (int nt=0; nt<8; ++nt) bia[nt] = bias4[n0 + wn*128 + nt*16 + lr];
  #pragma unroll
  for (int mt=0; mt<4; ++mt){
    #pragma unroll
    for (int nt=0; nt<8; ++nt){
      #pragma unroll
      for (int r=0; r<4; ++r){
        int row = m0 + wm*64 + mt*16 + lk*4 + r;
        int col = n0 + wn*128 + nt*16 + lr;
        _Float16 hv = (_Float16)(acc[mt][nt][r] + bia[nt]);
        xh[(size_t)row*NG + col] = __builtin_bit_cast(unsigned short, hv);
      }
    }
  }
}

// LSTM chunk. 64 WGs x 512 threads (8 waves, 2/SIMD).
// wave wv: kq=wv>>1 (col slice 64), jh=wv&1 (row half). thread l: rows jh*512+l*8+r.
// Weight residency (256 pairs/thread), ALL on-CU, zero streaming:
//   cp in [0,8)   -> LDS wlds4[16][512] (128 KB)
//   cp in [8,24)  -> EXACTLY 128 AGPRs (the unified-file split observed across
//                    rounds 2-8 is arch 128 + AGPR 128; round 8's 192 AGPRs
//                    overflowed by 64 and thrashed scratch)
//   cp in [24,32) -> 64 arch VGPRs (laundered), total arch demand ~95 < 128
__global__ __attribute__((amdgpu_flat_work_group_size(512,512)))
__attribute__((amdgpu_waves_per_eu(2,2)))
void k_rnn(const unsigned short* __restrict__ xh,
           const uint4* __restrict__ pall4,
           const float* __restrict__ h0,
           const float* __restrict__ c0,
           const int* __restrict__ seqlen,
           const float* __restrict__ lin_w,
           const float* __restrict__ lin_b,
           unsigned int* __restrict__ h_ws,
           float* __restrict__ c_ws,
           float* __restrict__ ms_ws,
           float* __restrict__ out,
           int t0, int tcount, int is_first, int is_last){
  __shared__ uint4 wlds4[16][512];          // 128 KB: weight pairs for cp in [0,8)
  __shared__ unsigned int hp[128];          // h as f16 pairs
  __shared__ float part2[4][2][8][68];      // [kq][jh][r][l] pitch 68
  __shared__ float red[256];
  const int b   = blockIdx.x;
  const int tid = threadIdx.x;
  const int l   = tid & 63, wv = tid >> 6;
  const int kq  = wv >> 1, jh = wv & 1;

  // stage LDS-resident weights (j = 0..15 -> cp in [0,8))
  #pragma unroll
  for (int jj=0; jj<16; ++jj)
    wlds4[jj][tid] = pall4[(size_t)jj*512 + tid];

  // AGPR-resident weights (j = 16..47 -> cp in [8,24)): wa[4*(j-16)+e]
  unsigned int wa[128];
  #pragma unroll
  for (int j=16; j<48; ++j){
    uint4 v = pall4[(size_t)j*512 + tid];
    asm volatile("v_accvgpr_write_b32 %0, %1" : "=a"(wa[4*(j-16)+0]) : "v"(v.x));
    asm volatile("v_accvgpr_write_b32 %0, %1" : "=a"(wa[4*(j-16)+1]) : "v"(v.y));
    asm volatile("v_accvgpr_write_b32 %0, %1" : "=a"(wa[4*(j-16)+2]) : "v"(v.z));
    asm volatile("v_accvgpr_write_b32 %0, %1" : "=a"(wa[4*(j-16)+3]) : "v"(v.w));
  }

  // arch-resident weights (j = 48..63 -> cp in [24,32)): wres[4*(j-48)+e]
  unsigned int wres[64];
  #pragma unroll
  for (int j=48; j<64; ++j){
    uint4 v = pall4[(size_t)j*512 + tid];
    wres[4*(j-48)+0]=v.x; wres[4*(j-48)+1]=v.y; wres[4*(j-48)+2]=v.z; wres[4*(j-48)+3]=v.w;
  }
  #pragma unroll
  for (int i=0;i<64;++i) asm volatile("" : "+v"(wres[i]));

  float creg = 0.f, msum = 0.f;
  if (is_first){
    if (tid < 128) hp[tid] = packh2(h0[(size_t)b*NH + 2*tid], h0[(size_t)b*NH + 2*tid + 1]);
    if (tid < 256) creg = c0[(size_t)b*NH + tid];
  } else {
    if (tid < 128) hp[tid] = h_ws[b*128 + tid];
    if (tid < 256){ creg = c_ws[b*256 + tid]; msum = ms_ws[b*256 + tid]; }
  }
  const int L = seqlen[b];
  __syncthreads();

  const unsigned short* xrow = xh + (size_t)b*NG + tid;

  for (int tl=0; tl<tcount; ++tl){
    // ---- prefetch xg for this step (raw; converted after barrier) ----
    unsigned short xr0=0, xr1=0, xr2=0, xr3=0;
    if (tid < 256){
      const unsigned short* xr = xrow + (size_t)tl*NB*NG;
      xr0 = xr[0]; xr1 = xr[256]; xr2 = xr[512]; xr3 = xr[768];
    }

    float pa[8];
    #pragma unroll
    for (int r=0;r<8;++r) pa[r]=0.f;

    // ---- cp in [0,8): LDS weights ----
    #pragma unroll
    for (int j=0;j<16;++j){
      uint4 v = wlds4[j][tid];
      unsigned int w4[4] = {v.x, v.y, v.z, v.w};
      #pragma unroll
      for (int e=0;e<4;++e){
        int idx = 4*j+e, cp = idx>>3, r = idx&7;
        pa[r] = dot2_acc(w4[e], hp[kq*32+cp], pa[r]);
      }
    }

    // ---- cp in [8,24): AGPR weights ----
    #pragma unroll
    for (int cp=8; cp<24; ++cp){
      unsigned int hpv = hp[kq*32 + cp];
      #pragma unroll
      for (int r=0; r<8; ++r){
        unsigned int t;
        asm volatile("v_accvgpr_read_b32 %0, %1" : "=v"(t) : "a"(wa[(cp-8)*8 + r]));
        pa[r] = dot2_acc(t, hpv, pa[r]);
      }
    }

    // ---- cp in [24,32): arch-VGPR weights ----
    #pragma unroll
    for (int cp=24; cp<32; ++cp){
      unsigned int hpv = hp[kq*32 + cp];
      #pragma unroll
      for (int r=0;r<8;++r) pa[r] = dot2_acc(wres[(cp-24)*8+r], hpv, pa[r]);
    }

    #pragma unroll
    for (int r=0;r<8;++r) part2[kq][jh][r][l] = pa[r];
    __syncthreads();

    if (tid < 256){
      unsigned short xr4[4] = {xr0, xr1, xr2, xr3};
      float a[4];
      #pragma unroll
      for (int q=0;q<4;++q){
        int G = q*256 + tid;
        int jh2 = G>>9, rw = G&511, l2 = rw>>3, r2 = rw&7;
        float s = (float)__builtin_bit_cast(_Float16, xr4[q]);
        #pragma unroll
        for (int k=0;k<4;++k) s += part2[k][jh2][r2][l2];
        a[q] = s;
      }
      float si = sigm(a[0]), sf = sigm(a[1]), so = sigm(a[3]);
      float tg = tanh_(a[2]);
      creg = sf*creg + si*tg;
      float h2 = so*tanh_(creg);
      if (t0 + tl < L) msum += h2;
      ((_Float16*)hp)[tid] = (_Float16)h2;
    }
    __syncthreads();
  }

  if (tid < 128) h_ws[b*128 + tid] = hp[tid];
  if (tid < 256){ c_ws[b*256 + tid] = creg; ms_ws[b*256 + tid] = msum; }

  if (is_last){
    if (tid < 256) red[tid] = (msum / (float)L) * lin_w[tid];
    __syncthreads();
    if (tid < 64){
      float s = red[tid] + red[tid+64] + red[tid+128] + red[tid+192];
      #pragma unroll
      for (int off=32; off>0; off>>=1) s += __shfl_down(s, off);
      if (tid==0) out[b] = sigm(s + lin_b[0]);
    }
  }
}

extern "C" void kernel_launch(void* const* d_in, const int* in_sizes, int n_in,
                              void* d_out, int out_size, void* d_ws, size_t ws_size,
                              hipStream_t stream){
  const int*   ipts   = (const int*)d_in[0];
  const int*   seqlen = (const int*)d_in[1];
  const float* h0     = (const float*)d_in[2];
  const float* c0     = (const float*)d_in[3];
  const float* emb    = (const float*)d_in[4];
  const float* conv_w = (const float*)d_in[5];
  const float* conv_b = (const float*)d_in[6];
  const float* w_ih   = (const float*)d_in[7];
  const float* w_hh   = (const float*)d_in[8];
  const float* b_ih   = (const float*)d_in[9];
  const float* b_hh   = (const float*)d_in[10];
  const float* lin_w  = (const float*)d_in[11];
  const float* lin_b  = (const float*)d_in[12];
  float* out = (float*)d_out;

  char* ws = (char*)d_ws;
  const size_t XH_B   = (size_t)TC*NB*NG*2;      // 33.5 MB
  const size_t CW2_B  = (size_t)NG*768*2;        // 1.57 MB
  const size_t PALL_B = (size_t)64*512*16;       // 512 KB
  unsigned short* xh    = (unsigned short*)ws;
  unsigned short* cw2t  = (unsigned short*)(ws + XH_B);
  uint4*          pall4 = (uint4*)(ws + XH_B + CW2_B);
  float*          bias4 = (float*)(ws + XH_B + CW2_B + PALL_B);
  unsigned int*   h_ws  = (unsigned int*)(ws + XH_B + CW2_B + PALL_B + 4096);
  float*          c_ws  = (float*)(ws + XH_B + CW2_B + PALL_B + 4096 + 32768);
  float*          ms_ws = (float*)(ws + XH_B + CW2_B + PALL_B + 4096 + 32768 + 65536);

  k_bias<<<dim3(4),       dim3(256), 0, stream>>>(conv_b, w_ih, b_ih, b_hh, bias4);
  k_pack<<<dim3(128),     dim3(256), 0, stream>>>(w_hh, pall4);
  k_cw2 <<<dim3(12, 16),  dim3(256), 0, stream>>>(w_ih, conv_w, cw2t);

  for (int t0 = 0; t0 < TLEN; t0 += TC){
    int tcount = (TLEN - t0 < TC) ? (TLEN - t0) : TC;
    int is_first = (t0 == 0), is_last = (t0 + TC >= TLEN);
    k_fxg<<<dim3(128, 4), dim3(256), 0, stream>>>(ipts, emb, cw2t, bias4, xh, t0);
    k_rnn<<<dim3(NB),     dim3(512), 0, stream>>>(xh, pall4, h0, c0, seqlen,
                                                  lin_w, lin_b, h_ws, c_ws, ms_ws, out,
                                                  t0, tcount, is_first, is_last);
  }
}